// Round 1
// baseline (199.729 us; speedup 1.0000x reference)
//
#include <hip/hip_runtime.h>
#include <cstdint>

constexpr int GN  = 41;                 // grid points per dim
constexpr int VOX = GN * GN * GN;       // 68921 spatial points
constexpr int CH  = 32;                 // channels
constexpr int EF  = 128;                // encoder features

// -------- Pass 1: transpose grid [C][X][Y][Z] -> [X][Y][Z][C] into d_ws ----
__global__ void transpose_grid_k(const float* __restrict__ src,
                                 float* __restrict__ dst, int total) {
    int idx = blockIdx.x * 256 + threadIdx.x;   // idx = spatial*32 + c
    if (idx >= total) return;
    int c = idx & (CH - 1);
    int s = idx >> 5;
    dst[idx] = src[c * VOX + s];
}

// Cubic B-spline weights: w_j = sum_k [1,t,t^2,t^3]_k * M[k][j], M = 1/6 * ...
__device__ __forceinline__ void bspline_w(float t, float w[4]) {
    float t2 = t * t, t3 = t2 * t;
    const float k = 1.0f / 6.0f;
    w[0] = k * (1.0f - 3.0f * t + 3.0f * t2 - t3);
    w[1] = k * (4.0f - 6.0f * t2 + 3.0f * t3);
    w[2] = k * (1.0f + 3.0f * t + 3.0f * t2 - 3.0f * t3);
    w[3] = k * t3;
}

// -------- Pass 2: one wave per batch element -------------------------------
// lane = zslice(2b) | cpair(4b): lane>>4 = z offset 0..3, (lane&15)*2 = channel
// Each (i,j) row load: 64 lanes x float2 = 512B contiguous chunk [4z][32c].
__global__ __launch_bounds__(256, 4) void lig_main(
    const float* __restrict__ nb, const float* __restrict__ gT,
    const float* __restrict__ enc_w, const float* __restrict__ enc_b,
    float* __restrict__ out, int batch) {

    const int lane = threadIdx.x & 63;
    const int wid  = blockIdx.x * (blockDim.x >> 6) + (threadIdx.x >> 6);
    const int nw   = gridDim.x * (blockDim.x >> 6);

    // enc_w rows f0=2*lane, f0+1 held in registers (64 VGPRs), reused per wave
    const int f0 = 2 * lane;
    float4 ew0[8], ew1[8];
    const float4* w4 = reinterpret_cast<const float4*>(enc_w);
#pragma unroll
    for (int q = 0; q < 8; ++q) {
        ew0[q] = w4[f0 * 8 + q];
        ew1[q] = w4[f0 * 8 + 8 + q];
    }
    const float bb0 = enc_b[f0], bb1 = enc_b[f0 + 1];

    const int zsl = lane >> 4;
    const int cp  = (lane & 15) * 2;

    for (int e = wid; e < batch; e += nw) {
        // normalize + clip coords (wave-uniform scalar work)
        float p0 = nb[3 * e], p1 = nb[3 * e + 1], p2 = nb[3 * e + 2];
        float ux = fminf(fmaxf(0.5f + 0.1f * p0, 0.0f), 1.0f) * 40.0f;
        float uy = fminf(fmaxf(0.5f + 0.1f * p1, 0.0f), 1.0f) * 40.0f;
        float uz = fminf(fmaxf(0.5f + 0.1f * p2, 0.0f), 1.0f) * 40.0f;
        int bx = (int)ux, by = (int)uy, bz = (int)uz;  // floor (u >= 0)
        float wx[4], wy[4], wz[4];
        bspline_w(ux - (float)bx, wx);
        bspline_w(uy - (float)by, wy);
        bspline_w(uz - (float)bz, wz);

        int X[4], Y[4];
#pragma unroll
        for (int o = 0; o < 4; ++o) {
            X[o] = min(max(bx + o - 1, 0), GN - 1) * (GN * GN * CH);
            Y[o] = min(max(by + o - 1, 0), GN - 1) * (GN * CH);
        }
        // per-lane z offset (clamped) + channel offset
        int   Zl  = min(max(bz + zsl - 1, 0), GN - 1) * CH + cp;
        float wzl = wz[zsl];

        float acc0 = 0.0f, acc1 = 0.0f;
#pragma unroll
        for (int i = 0; i < 4; ++i) {
            float wxi = wx[i];
#pragma unroll
            for (int j = 0; j < 4; ++j) {
                const float2 v =
                    *reinterpret_cast<const float2*>(gT + (X[i] + Y[j] + Zl));
                float w = wxi * wy[j];
                acc0 = fmaf(w, v.x, acc0);
                acc1 = fmaf(w, v.y, acc1);
            }
        }
        acc0 *= wzl;  // hoisted z-weight (B-spline sum is separable)
        acc1 *= wzl;

        // reduce over the 4 z-slices (lanes l, l^16, l^32, l^48 share channels)
        acc0 += __shfl_xor(acc0, 16);
        acc0 += __shfl_xor(acc0, 32);
        acc1 += __shfl_xor(acc1, 16);
        acc1 += __shfl_xor(acc1, 32);

        // 32 -> 128 matmul: readlane-broadcast lig_x, scalar-operand FMAs
        float o0 = bb0, o1 = bb1;
#pragma unroll
        for (int q = 0; q < 8; ++q) {
            float a0 = __shfl(acc0, 2 * q);      // channel 4q
            float a1 = __shfl(acc1, 2 * q);      // channel 4q+1
            float a2 = __shfl(acc0, 2 * q + 1);  // channel 4q+2
            float a3 = __shfl(acc1, 2 * q + 1);  // channel 4q+3
            o0 = fmaf(a0, ew0[q].x, o0);
            o0 = fmaf(a1, ew0[q].y, o0);
            o0 = fmaf(a2, ew0[q].z, o0);
            o0 = fmaf(a3, ew0[q].w, o0);
            o1 = fmaf(a0, ew1[q].x, o1);
            o1 = fmaf(a1, ew1[q].y, o1);
            o1 = fmaf(a2, ew1[q].z, o1);
            o1 = fmaf(a3, ew1[q].w, o1);
        }
        // coalesced float2 store: out[e][2*lane .. 2*lane+1]
        reinterpret_cast<float2*>(out + (size_t)e * EF)[lane] =
            make_float2(o0, o1);
    }
}

extern "C" void kernel_launch(void* const* d_in, const int* in_sizes, int n_in,
                              void* d_out, int out_size, void* d_ws,
                              size_t ws_size, hipStream_t stream) {
    const float* nb   = (const float*)d_in[0];
    const float* grid = (const float*)d_in[1];
    const float* ew   = (const float*)d_in[2];
    const float* eb   = (const float*)d_in[3];
    float*       out  = (float*)d_out;
    float*       gT   = (float*)d_ws;  // needs VOX*CH*4 = 8.4 MiB

    int batch = in_sizes[0] / 3;
    int total = VOX * CH;

    transpose_grid_k<<<(total + 255) / 256, 256, 0, stream>>>(grid, gT, total);
    lig_main<<<1024, 256, 0, stream>>>(nb, gT, ew, eb, out, batch);
}